// Round 12
// baseline (496.481 us; speedup 1.0000x reference)
//
#include <hip/hip_runtime.h>
#include <hip/hip_bf16.h>
#include <math.h>

#define BB 16
#define CC 512
#define NH 8
#define HD 64
#define NN 1024   // H*W
#define THREEC 1536

// Q pre-scale: (1/sqrt(64)) * log2(e)  -> softmax via raw v_exp_f32 (2^x)
#define QSCALE 0.18033688f

typedef __attribute__((ext_vector_type(8))) short bf16x8;
typedef __attribute__((ext_vector_type(4))) float f32x4;
typedef __attribute__((ext_vector_type(16))) float f32x16;

#if __has_builtin(__builtin_amdgcn_exp2f)
#define EXP2F __builtin_amdgcn_exp2f
#else
#define EXP2F exp2f
#endif

// workspace byte offsets
#define XT_OFF 0u           // bf16 x^T [b][n][c]          (16.78 MB)
#define WQ_OFF 16777216u    // bf16 w_qkv [1536][512]      (1.57 MB)
#define WP_OFF 18350080u    // bf16 w_proj [512][512]      (0.52 MB)
#define QB_OFF 18874368u    // bf16 Q (scaled QSCALE) [bh][n][d]
#define KB_OFF 35651584u    // bf16 K [bh][n][d]
#define VT_OFF 52428800u    // bf16 V^T [bh][d][n]
#define AB_OFF 69206016u    // bf16 attn-out [b][n][c]
// end 85983232 (82 MiB)

static __device__ inline unsigned short f2bf(float f) {
  union { float f; unsigned u; } v; v.f = f;
  unsigned r = v.u + 0x7fffu + ((v.u >> 16) & 1u);
  return (unsigned short)(r >> 16);
}

// pack two f32 -> two bf16 in a u32 (lo = a, hi = b)
static __device__ inline unsigned pk2bf(float a, float b) {
#if defined(__AMDGCN__) && __has_builtin(__builtin_amdgcn_cvt_pk_bf16_f32)
  typedef __attribute__((ext_vector_type(2))) __bf16 bfp2;
  union { bfp2 v; unsigned u; } z;
  z.v = __builtin_amdgcn_cvt_pk_bf16_f32(a, b);
  return z.u;
#else
  return (unsigned)f2bf(a) | ((unsigned)f2bf(b) << 16);
#endif
}

static __device__ inline void gld_lds16(const unsigned short* g, unsigned short* l) {
  __builtin_amdgcn_global_load_lds(
      (const __attribute__((address_space(1))) unsigned int*)g,
      (__attribute__((address_space(3))) unsigned int*)l, 16, 0, 0);
}

// ---------------------------------------------------------------------------
// prep_fused: x [b][c][n] fp32 -> xT [b][n][c] bf16 (64x64 LDS transpose),
// PLUS (first 512 blocks) w_qkv/w_proj fp32 -> bf16 conversion folded in.
// ---------------------------------------------------------------------------
__global__ __launch_bounds__(256) void prep_fused(const float* __restrict__ x,
                                                  unsigned short* __restrict__ xT,
                                                  const float* __restrict__ wqkv,
                                                  const float* __restrict__ wproj,
                                                  unsigned short* __restrict__ dq,
                                                  unsigned short* __restrict__ dp) {
  const int b  = blockIdx.z;
  const int c0 = blockIdx.y * 64;
  const int n0 = blockIdx.x * 64;
  __shared__ float tile[64][65];
  const int t  = threadIdx.x;

  // ---- folded prep_w: blocks with wid < 512 ----
  const int wid = (blockIdx.z * 8 + blockIdx.y) * 16 + blockIdx.x;
  if (wid < 512) {
    const size_t i8 = ((size_t)wid * 256 + t) * 8;
    const float* src;
    unsigned short* dst;
    if (i8 < 786432u) { src = wqkv + i8; dst = dq + i8; }
    else              { src = wproj + (i8 - 786432u); dst = dp + (i8 - 786432u); }
    float4 a = *(const float4*)src;
    float4 b4 = *(const float4*)(src + 4);
    unsigned short pk[8] = {f2bf(a.x), f2bf(a.y), f2bf(a.z), f2bf(a.w),
                            f2bf(b4.x), f2bf(b4.y), f2bf(b4.z), f2bf(b4.w)};
    *(uint4*)dst = *(const uint4*)pk;
  }

  // ---- xT transpose ----
  const int cl = t >> 4, n4 = (t & 15) * 4;
#pragma unroll
  for (int r = 0; r < 4; ++r) {
    float4 v = *(const float4*)&x[((size_t)b * CC + c0 + cl + 16 * r) * NN + n0 + n4];
    *(float4*)&tile[cl + 16 * r][n4] = v;
  }
  __syncthreads();
  const int nl = t >> 4, c4 = (t & 15) * 4;
#pragma unroll
  for (int r = 0; r < 4; ++r) {
    ushort4 p;
    p.x = f2bf(tile[c4 + 0][nl + 16 * r]);
    p.y = f2bf(tile[c4 + 1][nl + 16 * r]);
    p.z = f2bf(tile[c4 + 2][nl + 16 * r]);
    p.w = f2bf(tile[c4 + 3][nl + 16 * r]);
    *(ushort4*)&xT[((size_t)b * NN + n0 + nl + 16 * r) * CC + c0 + c4] = p;
  }
}

// ---------------------------------------------------------------------------
// qkv_mfma: [1536x512] @ [512x1024] per batch, bf16 MFMA, 128x128 tile BK=64.
// ---------------------------------------------------------------------------
__global__ __launch_bounds__(256) void qkv_mfma(const unsigned short* __restrict__ wq,
                                                const unsigned short* __restrict__ xT,
                                                unsigned short* __restrict__ qb,
                                                unsigned short* __restrict__ kb_,
                                                unsigned short* __restrict__ vt) {
  const int b  = blockIdx.z;
  const int o0 = blockIdx.y * 128;
  const int n0 = blockIdx.x * 128;
  const int t  = threadIdx.x;
  const int w    = t >> 6;
  const int lane = t & 63;
  const int quad = lane >> 4;
  const int l16  = lane & 15;
  const int m_off = (w >> 1) * 64;
  const int n_off = (w & 1) * 64;

  __shared__ unsigned short sm[17408];
  unsigned short* As = sm;
  unsigned short* Bs = sm + 8192;

  const int which = o0 >> 9;       // 0=Q,1=K,2=V
  const bool vmode = (which == 2);

  const int srow = lane >> 3;
  const int ssw  = ((lane & 7) ^ srow) * 8;
  const unsigned short* gA = wq + (size_t)(o0 + 32 * w + srow) * CC + ssw;
  const unsigned short* gB = xT + ((size_t)b * NN + n0 + 32 * w + srow) * CC + ssw;

  f32x4 acc[4][4] = {};

  for (int c0 = 0; c0 < CC; c0 += 64) {
    __syncthreads();
#pragma unroll
    for (int L = 0; L < 4; ++L) {
      gld_lds16(gA + (size_t)(8 * L) * CC + c0, &As[(32 * w + 8 * L) * 64]);
      gld_lds16(gB + (size_t)(8 * L) * CC + c0, &Bs[(32 * w + 8 * L) * 64]);
    }
    __syncthreads();
    const unsigned short* Af = vmode ? Bs : As;
    const unsigned short* Bf = vmode ? As : Bs;
#pragma unroll
    for (int ks = 0; ks < 2; ++ks) {
      const int ph = ((ks * 4 + quad) ^ (l16 & 7)) * 8;
      bf16x8 af[4], bfr[4];
#pragma unroll
      for (int i = 0; i < 4; ++i) {
        af[i]  = *(const bf16x8*)&Af[(m_off + 16 * i + l16) * 64 + ph];
        bfr[i] = *(const bf16x8*)&Bf[(n_off + 16 * i + l16) * 64 + ph];
      }
#pragma unroll
      for (int i = 0; i < 4; ++i)
#pragma unroll
        for (int j = 0; j < 4; ++j)
          acc[i][j] = __builtin_amdgcn_mfma_f32_16x16x32_bf16(af[i], bfr[j], acc[i][j], 0, 0, 0);
    }
  }

  __syncthreads();
  const float sc = (which == 0) ? QSCALE : 1.0f;
#pragma unroll
  for (int i = 0; i < 4; ++i) {
#pragma unroll
    for (int j = 0; j < 4; ++j) {
      const int Drow = m_off + 16 * i + quad * 4;
      const int Dcol = n_off + 16 * j + l16;
      ushort4 p;
      p.x = f2bf(acc[i][j][0] * sc);
      p.y = f2bf(acc[i][j][1] * sc);
      p.z = f2bf(acc[i][j][2] * sc);
      p.w = f2bf(acc[i][j][3] * sc);
      *(ushort4*)&sm[Dcol * 136 + Drow] = p;
    }
  }
  __syncthreads();
  const int lrow = t >> 1;
  const int half = t & 1;
  const unsigned short* src = &sm[lrow * 136 + 64 * half];
  if (!vmode) {
    const int hh = ((o0 >> 6) & 7) + half;
    unsigned short* dst = (which == 0 ? qb : kb_) +
        ((size_t)(b * NH + hh) * NN + n0 + lrow) * HD;
#pragma unroll
    for (int i = 0; i < 8; ++i) *(uint4*)(dst + 8 * i) = *(const uint4*)(src + 8 * i);
  } else {
    const int hh = ((o0 + lrow) >> 6) & 7;
    const int d  = lrow & 63;
    unsigned short* dst = vt + ((size_t)(b * NH + hh) * HD + d) * NN + n0 + 64 * half;
#pragma unroll
    for (int i = 0; i < 8; ++i) *(uint4*)(dst + 8 * i) = *(const uint4*)(src + 8 * i);
  }
}

// ---------------------------------------------------------------------------
// attn_mfma v13: INTRA-BLOCK SPLIT-K over keys for 4 waves/SIMD occupancy.
// R11 state: v9 latency-bound at 2 waves/SIMD (geometric cap: 2048 waves),
// ~60% dependency stall, intra-wave ILP unfixable at source (v10/v12).
// v13: 512-thread blocks; waves 0-3 (split 0) process keys [0,512), waves
// 4-7 (split 1) keys [512,1024), same 256 queries. Max-free exp2 softmax
// makes the combine exact: O = O0+O1, l = l0+l1 (no rescaling). Per-split
// loop = v8's proven chunk-64 dbuf body verbatim (32KB/split, 64KB total
// -> still 2 blocks/CU), so LDS reads, staging, FETCH all unchanged —
// but total waves double to 4096 = 4 waves/SIMD, doubling latency hiding.
// Grid 512 blocks = exactly 2/CU x 256 CU, zero tail. Combine: 2 LDS
// passes (stride-34 float2 = 2-way bank = free), 5 barriers.
// ---------------------------------------------------------------------------
__global__ __launch_bounds__(512, 4) void attn_mfma(const unsigned short* __restrict__ Qg,
                                                    const unsigned short* __restrict__ Kg,
                                                    const unsigned short* __restrict__ Vtg,
                                                    unsigned short* __restrict__ attnB) {
  const int bh = blockIdx.x;     // id % 8 == bh % 8 -> XCD affinity
  const int b  = bh >> 3;
  const int h  = bh & 7;
  const int n0 = blockIdx.y * 256;
  const int t  = threadIdx.x;
  const int w    = t >> 6;        // 0..7
  const int s    = w >> 2;        // key-split 0/1
  const int ws   = w & 3;         // wave-in-split 0..3
  const int lane = t & 63;
  const int l31  = lane & 31;
  const int hi   = lane >> 5;

  // K bufs: (2s+p)*4096 shorts (sm[0,16384));  V bufs: 16384 + (2s+p)*4096
  __shared__ unsigned short sm[32768];   // 64 KiB

  // two query groups per wave: A = n0 + ws*64 + l31, B = A + 32
  const unsigned short* qrow = Qg + ((size_t)bh * NN + n0 + ws * 64 + l31) * HD + hi * 8;
  bf16x8 qfA[4], qfB[4];
#pragma unroll
  for (int c = 0; c < 4; ++c) {
    qfA[c] = *(const bf16x8*)(qrow + 16 * c);
    qfB[c] = *(const bf16x8*)(qrow + 32 * HD + 16 * c);
  }

  // K A-row permutation: rho(l) swaps bits 2 and 3
  const int krow = (l31 & ~12) | ((l31 & 4) << 1) | ((l31 & 8) >> 1);
  const int ksw  = (krow >> 2) & 7;
  const int vsw  = (l31 >> 2) & 7;

  const f32x16 fz = {};
  f32x16 oaccA[2] = {}, oaccB[2] = {};   // O^T partial: D[m=d][n=query]
  float lxA = 0.f, lyA = 0.f, lxB = 0.f, lyB = 0.f;

  // staging (v8 pattern per split, chunk=64): wave ws covers rows
  // [16ws,16ws+16) of K (keys rel. to split) and V^T (d). Source col
  // pre-swizzled with the (row>>2) involution.
  const int srow = lane >> 3;                     // 0..7
  const int sgA  = (lane & 7) ^ ((4 * ws + (srow >> 2)) & 7);
  const int sgB  = (lane & 7) ^ ((4 * ws + 2 + (srow >> 2)) & 7);
  const int kbase = s * 512;                      // this split's key offset
  const unsigned short* kstA = Kg + (size_t)bh * NN * HD +
                               (size_t)(kbase + 16 * ws + srow) * HD + sgA * 8;
  const unsigned short* kstB = Kg + (size_t)bh * NN * HD +
                               (size_t)(kbase + 16 * ws + 8 + srow) * HD + sgB * 8;
  const unsigned short* vstA = Vtg + (size_t)bh * HD * NN +
                               (size_t)(16 * ws + srow) * NN + kbase + sgA * 8;
  const unsigned short* vstB = Vtg + (size_t)bh * HD * NN +
                               (size_t)(16 * ws + 8 + srow) * NN + kbase + sgB * 8;
  const int kso0 = (16 * ws) * 64;
  const int kso1 = (16 * ws + 8) * 64;

  // stage one 64-key chunk (rel. offset j0 in [0,512)) into split buffer p
  auto stage = [&](int j0, int p) {
    unsigned short* Kp = sm + (2 * s + p) * 4096;
    unsigned short* Vp = sm + 16384 + (2 * s + p) * 4096;
    gld_lds16(kstA + (size_t)j0 * HD, Kp + kso0);
    gld_lds16(kstB + (size_t)j0 * HD, Kp + kso1);
    gld_lds16(vstA + j0, Vp + kso0);
    gld_lds16(vstB + j0, Vp + kso1);
  };

  // prologue: chunk 0 into buffer 0
  stage(0, 0);
  int cur = 0;

#pragma unroll 1
  for (int j0 = 0; j0 < 512; j0 += 64) {
    // implicit s_waitcnt vmcnt(0) here drains chunk-j0 loads (in flight for
    // a full compute phase), then publishes them to all waves.
    __syncthreads();
    if (j0 + 64 < 512) stage(j0 + 64, cur ^ 1);

    const unsigned short* Ks = sm + (2 * s + cur) * 4096;          // [key][d]
    const unsigned short* Vt = sm + 16384 + (2 * s + cur) * 4096;  // [d][key]

#pragma unroll
    for (int kb = 0; kb < 2; ++kb) {
      // S^T: A[m]=K row rho(m) (32 keys), B=Q; contract over d.
      // kf read ONCE from LDS, feeds both query groups.
      const unsigned short* krp = &Ks[(32 * kb + krow) * 64];
      __builtin_amdgcn_s_setprio(1);
      bf16x8 kf0 = *(const bf16x8*)(krp + (((0 + hi) ^ ksw) * 8));
      f32x16 stA = __builtin_amdgcn_mfma_f32_32x32x16_bf16(kf0, qfA[0], fz, 0, 0, 0);
      f32x16 stB = __builtin_amdgcn_mfma_f32_32x32x16_bf16(kf0, qfB[0], fz, 0, 0, 0);
#pragma unroll
      for (int c = 1; c < 4; ++c) {
        bf16x8 kf = *(const bf16x8*)(krp + (((2 * c + hi) ^ ksw) * 8));
        stA = __builtin_amdgcn_mfma_f32_32x32x16_bf16(kf, qfA[c], stA, 0, 0, 0);
        stB = __builtin_amdgcn_mfma_f32_32x32x16_bf16(kf, qfB[c], stB, 0, 0, 0);
      }
      __builtin_amdgcn_s_setprio(0);
      // exp2 (Q carries log2e/8) + l accum + pack; P pairs ARE the PV
      // B-fragment (key permutation absorbed rho)
      unsigned PA[8], PB[8];
#pragma unroll
      for (int i = 0; i < 8; ++i) {
        float ea = EXP2F(stA[2 * i]);
        float eb = EXP2F(stA[2 * i + 1]);
        lxA += ea; lyA += eb;
        PA[i] = pk2bf(ea, eb);
      }
#pragma unroll
      for (int i = 0; i < 8; ++i) {
        float ea = EXP2F(stB[2 * i]);
        float eb = EXP2F(stB[2 * i + 1]);
        lxB += ea; lyB += eb;
        PB[i] = pk2bf(ea, eb);
      }

      __builtin_amdgcn_s_setprio(1);
#pragma unroll
      for (int g = 0; g < 2; ++g) {
        union { unsigned u[4]; bf16x8 v; } cvA, cvB;
        cvA.u[0] = PA[4 * g + 0]; cvA.u[1] = PA[4 * g + 1];
        cvA.u[2] = PA[4 * g + 2]; cvA.u[3] = PA[4 * g + 3];
        cvB.u[0] = PB[4 * g + 0]; cvB.u[1] = PB[4 * g + 1];
        cvB.u[2] = PB[4 * g + 2]; cvB.u[3] = PB[4 * g + 3];
#pragma unroll
        for (int mt = 0; mt < 2; ++mt) {
          const int vrow = 32 * mt + l31;
          // vf read ONCE from LDS, feeds both query groups.
          bf16x8 vf = *(const bf16x8*)&Vt[vrow * 64 + (((4 * kb + 2 * g + hi) ^ vsw) * 8)];
          oaccA[mt] = __builtin_amdgcn_mfma_f32_32x32x16_bf16(vf, cvA.v, oaccA[mt], 0, 0, 0);
          oaccB[mt] = __builtin_amdgcn_mfma_f32_32x32x16_bf16(vf, cvB.v, oaccB[mt], 0, 0, 0);
        }
      }
      __builtin_amdgcn_s_setprio(0);
    }
    cur ^= 1;
  }

  // ---- split combine: O = O0+O1, l = l0+l1 (exact: max-free softmax) ----
  float plA = lxA + lyA;           // per-lane partial l (pre-shuffle)
  float plB = lxB + lyB;
  float* CB = (float*)sm;
  // per wave-pair region: CB[ws*2176 .. +2176), layout lane*34 + idx
  // (stride 136B -> float2 writes land 2-way on banks = free).
  // l partials at CB[8704 + ws*128 + lane*2 + {0,1}].

  __syncthreads();                 // all compute + staging LDS reads done
  if (s == 1) {
    float* R = CB + ws * 2176;
#pragma unroll
    for (int mt = 0; mt < 2; ++mt)
#pragma unroll
      for (int r = 0; r < 8; ++r)
        *(float2*)&R[lane * 34 + mt * 16 + 2 * r] =
            make_float2(oaccA[mt][2 * r], oaccA[mt][2 * r + 1]);
    CB[8704 + ws * 128 + lane * 2 + 0] = plA;
    CB[8704 + ws * 128 + lane * 2 + 1] = plB;
  }
  __syncthreads();
  if (s == 0) {
    float* R = CB + ws * 2176;
#pragma unroll
    for (int mt = 0; mt < 2; ++mt)
#pragma unroll
      for (int r = 0; r < 8; ++r) {
        float2 v = *(const float2*)&R[lane * 34 + mt * 16 + 2 * r];
        oaccA[mt][2 * r]     += v.x;
        oaccA[mt][2 * r + 1] += v.y;
      }
    plA += CB[8704 + ws * 128 + lane * 2 + 0];
    plB += CB[8704 + ws * 128 + lane * 2 + 1];
  }
  __syncthreads();
  if (s == 1) {
    float* R = CB + ws * 2176;
#pragma unroll
    for (int mt = 0; mt < 2; ++mt)
#pragma unroll
      for (int r = 0; r < 8; ++r)
        *(float2*)&R[lane * 34 + mt * 16 + 2 * r] =
            make_float2(oaccB[mt][2 * r], oaccB[mt][2 * r + 1]);
  }
  __syncthreads();
  if (s == 0) {
    float* R = CB + ws * 2176;
#pragma unroll
    for (int mt = 0; mt < 2; ++mt)
#pragma unroll
      for (int r = 0; r < 8; ++r) {
        float2 v = *(const float2*)&R[lane * 34 + mt * 16 + 2 * r];
        oaccB[mt][2 * r]     += v.x;
        oaccB[mt][2 * r + 1] += v.y;
      }
  }
  __syncthreads();                 // all combine reads done; CB reusable

  // ---- final epilogue: split-0 waves only (they own the summed state) ----
  if (s == 0) {
    float lsA = plA;
    lsA += __shfl_xor(lsA, 32);
    const float invA = 1.0f / lsA;
    float lsB = plB;
    lsB += __shfl_xor(lsB, 32);
    const float invB = 1.0f / lsB;

    unsigned short* Es = sm + ws * 2304;   // 32 * 72 shorts per wave
    const int q    = lane >> 1;
    const int half = lane & 1;
    const unsigned short* esrc = &Es[q * 72 + 32 * half];

    // ---- pass A ----
#pragma unroll
    for (int mt = 0; mt < 2; ++mt) {
#pragma unroll
      for (int rr = 0; rr < 4; ++rr) {
        const int d = 32 * mt + 8 * rr + 4 * hi;
        ushort4 p;
        p.x = f2bf(oaccA[mt][4 * rr + 0] * invA);
        p.y = f2bf(oaccA[mt][4 * rr + 1] * invA);
        p.z = f2bf(oaccA[mt][4 * rr + 2] * invA);
        p.w = f2bf(oaccA[mt][4 * rr + 3] * invA);
        *(ushort4*)&Es[l31 * 72 + d] = p;
      }
    }
    {
      unsigned short* gdst = attnB + ((size_t)b * NN + n0 + ws * 64 + q) * CC + h * HD + 32 * half;
#pragma unroll
      for (int i = 0; i < 4; ++i) *(uint4*)(gdst + 8 * i) = *(const uint4*)(esrc + 8 * i);
    }

    // ---- pass B (same wave-private region; in-wave deps order LDS ops) ----
#pragma unroll
    for (int mt = 0; mt < 2; ++mt) {
#pragma unroll
      for (int rr = 0; rr < 4; ++rr) {
        const int d = 32 * mt + 8 * rr + 4 * hi;
        ushort4 p;
        p.x = f2bf(oaccB[mt][4 * rr + 0] * invB);
        p.y = f2bf(oaccB[mt][4 * rr + 1] * invB);
        p.z = f2bf(oaccB[mt][4 * rr + 2] * invB);
        p.w = f2bf(oaccB[mt][4 * rr + 3] * invB);
        *(ushort4*)&Es[l31 * 72 + d] = p;
      }
    }
    {
      unsigned short* gdst = attnB + ((size_t)b * NN + n0 + ws * 64 + 32 + q) * CC + h * HD + 32 * half;
#pragma unroll
      for (int i = 0; i < 4; ++i) *(uint4*)(gdst + 8 * i) = *(const uint4*)(esrc + 8 * i);
    }
  }
}

// ---------------------------------------------------------------------------
// proj_mfma: out = w_proj @ attn + bias, bf16 MFMA, fp32 out [b][c][n].
// ---------------------------------------------------------------------------
__global__ __launch_bounds__(256) void proj_mfma(const unsigned short* __restrict__ wp,
                                                 const unsigned short* __restrict__ aB,
                                                 const float* __restrict__ bias,
                                                 float* __restrict__ out) {
  const int b  = blockIdx.z;
  const int o0 = blockIdx.y * 128;
  const int n0 = blockIdx.x * 128;
  const int t  = threadIdx.x;
  const int w    = t >> 6;
  const int lane = t & 63;
  const int quad = lane >> 4;
  const int l16  = lane & 15;
  const int m_off = (w >> 1) * 64;
  const int n_off = (w & 1) * 64;

  __shared__ unsigned short sm[16384];
  unsigned short* As = sm;
  unsigned short* Bs = sm + 8192;

  const int srow = lane >> 3;
  const int ssw  = ((lane & 7) ^ srow) * 8;
  const unsigned short* gA = wp + (size_t)(o0 + 32 * w + srow) * CC + ssw;
  const unsigned short* gB = aB + ((size_t)b * NN + n0 + 32 * w + srow) * CC + ssw;

  f32x4 acc[4][4] = {};

  for (int c0 = 0; c0 < CC; c0 += 64) {
    __syncthreads();
#pragma unroll
    for (int L = 0; L < 4; ++L) {
      gld_lds16(gA + (size_t)(8 * L) * CC + c0, &As[(32 * w + 8 * L) * 64]);
      gld_lds16(gB + (size_t)(8 * L) * CC + c0, &Bs[(32 * w + 8 * L) * 64]);
    }
    __syncthreads();
#pragma unroll
    for (int ks = 0; ks < 2; ++ks) {
      const int ph = ((ks * 4 + quad) ^ (l16 & 7)) * 8;
      bf16x8 af[4], bfr[4];
#pragma unroll
      for (int i = 0; i < 4; ++i) {
        af[i]  = *(const bf16x8*)&As[(m_off + 16 * i + l16) * 64 + ph];
        bfr[i] = *(const bf16x8*)&Bs[(n_off + 16 * i + l16) * 64 + ph];
      }
#pragma unroll
      for (int i = 0; i < 4; ++i)
#pragma unroll
        for (int j = 0; j < 4; ++j)
          acc[i][j] = __builtin_amdgcn_mfma_f32_16x16x32_bf16(af[i], bfr[j], acc[i][j], 0, 0, 0);
    }
  }

#pragma unroll
  for (int i = 0; i < 4; ++i) {
#pragma unroll
    for (int r = 0; r < 4; ++r) {
      const int o = o0 + m_off + 16 * i + quad * 4 + r;
      const float bv = bias[o];
      float* orow = out + ((size_t)b * CC + o) * NN + n0 + n_off;
#pragma unroll
      for (int j = 0; j < 4; ++j)
        orow[16 * j + l16] = acc[i][j][r] + bv;
    }
  }
}

// ---------------------------------------------------------------------------
extern "C" void kernel_launch(void* const* d_in, const int* in_sizes, int n_in,
                              void* d_out, int out_size, void* d_ws, size_t ws_size,
                              hipStream_t stream) {
  const float* x      = (const float*)d_in[0];
  const float* w_qkv  = (const float*)d_in[1];
  const float* w_proj = (const float*)d_in[2];
  const float* b_proj = (const float*)d_in[3];
  char* wsb  = (char*)d_ws;
  float* out = (float*)d_out;

  unsigned short* xT  = (unsigned short*)(wsb + XT_OFF);
  unsigned short* wq  = (unsigned short*)(wsb + WQ_OFF);
  unsigned short* wp  = (unsigned short*)(wsb + WP_OFF);
  unsigned short* qb  = (unsigned short*)(wsb + QB_OFF);
  unsigned short* kb_ = (unsigned short*)(wsb + KB_OFF);
  unsigned short* vt  = (unsigned short*)(wsb + VT_OFF);
  unsigned short* aB  = (unsigned short*)(wsb + AB_OFF);

  prep_fused<<<dim3(16, 8, BB), 256, 0, stream>>>(x, xT, w_qkv, w_proj, wq, wp);
  qkv_mfma<<<dim3(8, 12, BB), 256, 0, stream>>>(wq, xT, qb, kb_, vt);
  attn_mfma<<<dim3(BB * NH, NN / 256), 512, 0, stream>>>(qb, kb_, vt, aB);
  proj_mfma<<<dim3(8, 4, BB), 256, 0, stream>>>(wp, aB, b_proj, out);
}

// Round 13
// 193.949 us; speedup vs baseline: 2.5599x; 2.5599x over previous
//
#include <hip/hip_runtime.h>
#include <hip/hip_bf16.h>
#include <math.h>

#define BB 16
#define CC 512
#define NH 8
#define HD 64
#define NN 1024   // H*W
#define THREEC 1536

// Q pre-scale: (1/sqrt(64)) * log2(e)  -> softmax via raw v_exp_f32 (2^x)
#define QSCALE 0.18033688f

typedef __attribute__((ext_vector_type(8))) short bf16x8;
typedef __attribute__((ext_vector_type(4))) float f32x4;
typedef __attribute__((ext_vector_type(16))) float f32x16;

#if __has_builtin(__builtin_amdgcn_exp2f)
#define EXP2F __builtin_amdgcn_exp2f
#else
#define EXP2F exp2f
#endif

// workspace byte offsets
#define XT_OFF 0u           // bf16 x^T [b][n][c]          (16.78 MB)
#define WQ_OFF 16777216u    // bf16 w_qkv [1536][512]      (1.57 MB)
#define WP_OFF 18350080u    // bf16 w_proj [512][512]      (0.52 MB)
#define QB_OFF 18874368u    // bf16 Q (scaled QSCALE) [bh][n][d]
#define KB_OFF 35651584u    // bf16 K [bh][n][d]
#define VT_OFF 52428800u    // bf16 V^T [bh][d][n]
#define AB_OFF 69206016u    // bf16 attn-out [b][n][c]
// end 85983232 (82 MiB)

static __device__ inline unsigned short f2bf(float f) {
  union { float f; unsigned u; } v; v.f = f;
  unsigned r = v.u + 0x7fffu + ((v.u >> 16) & 1u);
  return (unsigned short)(r >> 16);
}

// pack two f32 -> two bf16 in a u32 (lo = a, hi = b)
static __device__ inline unsigned pk2bf(float a, float b) {
#if defined(__AMDGCN__) && __has_builtin(__builtin_amdgcn_cvt_pk_bf16_f32)
  typedef __attribute__((ext_vector_type(2))) __bf16 bfp2;
  union { bfp2 v; unsigned u; } z;
  z.v = __builtin_amdgcn_cvt_pk_bf16_f32(a, b);
  return z.u;
#else
  return (unsigned)f2bf(a) | ((unsigned)f2bf(b) << 16);
#endif
}

static __device__ inline void gld_lds16(const unsigned short* g, unsigned short* l) {
  __builtin_amdgcn_global_load_lds(
      (const __attribute__((address_space(1))) unsigned int*)g,
      (__attribute__((address_space(3))) unsigned int*)l, 16, 0, 0);
}

// ---------------------------------------------------------------------------
// prep_fused: x [b][c][n] fp32 -> xT [b][n][c] bf16 (64x64 LDS transpose),
// PLUS (first 512 blocks) w_qkv/w_proj fp32 -> bf16 conversion folded in.
// ---------------------------------------------------------------------------
__global__ __launch_bounds__(256) void prep_fused(const float* __restrict__ x,
                                                  unsigned short* __restrict__ xT,
                                                  const float* __restrict__ wqkv,
                                                  const float* __restrict__ wproj,
                                                  unsigned short* __restrict__ dq,
                                                  unsigned short* __restrict__ dp) {
  const int b  = blockIdx.z;
  const int c0 = blockIdx.y * 64;
  const int n0 = blockIdx.x * 64;
  __shared__ float tile[64][65];
  const int t  = threadIdx.x;

  // ---- folded prep_w: blocks with wid < 512 ----
  const int wid = (blockIdx.z * 8 + blockIdx.y) * 16 + blockIdx.x;
  if (wid < 512) {
    const size_t i8 = ((size_t)wid * 256 + t) * 8;
    const float* src;
    unsigned short* dst;
    if (i8 < 786432u) { src = wqkv + i8; dst = dq + i8; }
    else              { src = wproj + (i8 - 786432u); dst = dp + (i8 - 786432u); }
    float4 a = *(const float4*)src;
    float4 b4 = *(const float4*)(src + 4);
    unsigned short pk[8] = {f2bf(a.x), f2bf(a.y), f2bf(a.z), f2bf(a.w),
                            f2bf(b4.x), f2bf(b4.y), f2bf(b4.z), f2bf(b4.w)};
    *(uint4*)dst = *(const uint4*)pk;
  }

  // ---- xT transpose ----
  const int cl = t >> 4, n4 = (t & 15) * 4;
#pragma unroll
  for (int r = 0; r < 4; ++r) {
    float4 v = *(const float4*)&x[((size_t)b * CC + c0 + cl + 16 * r) * NN + n0 + n4];
    *(float4*)&tile[cl + 16 * r][n4] = v;
  }
  __syncthreads();
  const int nl = t >> 4, c4 = (t & 15) * 4;
#pragma unroll
  for (int r = 0; r < 4; ++r) {
    ushort4 p;
    p.x = f2bf(tile[c4 + 0][nl + 16 * r]);
    p.y = f2bf(tile[c4 + 1][nl + 16 * r]);
    p.z = f2bf(tile[c4 + 2][nl + 16 * r]);
    p.w = f2bf(tile[c4 + 3][nl + 16 * r]);
    *(ushort4*)&xT[((size_t)b * NN + n0 + nl + 16 * r) * CC + c0 + c4] = p;
  }
}

// ---------------------------------------------------------------------------
// qkv_mfma: [1536x512] @ [512x1024] per batch, bf16 MFMA, 128x128 tile BK=64.
// ---------------------------------------------------------------------------
__global__ __launch_bounds__(256) void qkv_mfma(const unsigned short* __restrict__ wq,
                                                const unsigned short* __restrict__ xT,
                                                unsigned short* __restrict__ qb,
                                                unsigned short* __restrict__ kb_,
                                                unsigned short* __restrict__ vt) {
  const int b  = blockIdx.z;
  const int o0 = blockIdx.y * 128;
  const int n0 = blockIdx.x * 128;
  const int t  = threadIdx.x;
  const int w    = t >> 6;
  const int lane = t & 63;
  const int quad = lane >> 4;
  const int l16  = lane & 15;
  const int m_off = (w >> 1) * 64;
  const int n_off = (w & 1) * 64;

  __shared__ unsigned short sm[17408];
  unsigned short* As = sm;
  unsigned short* Bs = sm + 8192;

  const int which = o0 >> 9;       // 0=Q,1=K,2=V
  const bool vmode = (which == 2);

  const int srow = lane >> 3;
  const int ssw  = ((lane & 7) ^ srow) * 8;
  const unsigned short* gA = wq + (size_t)(o0 + 32 * w + srow) * CC + ssw;
  const unsigned short* gB = xT + ((size_t)b * NN + n0 + 32 * w + srow) * CC + ssw;

  f32x4 acc[4][4] = {};

  for (int c0 = 0; c0 < CC; c0 += 64) {
    __syncthreads();
#pragma unroll
    for (int L = 0; L < 4; ++L) {
      gld_lds16(gA + (size_t)(8 * L) * CC + c0, &As[(32 * w + 8 * L) * 64]);
      gld_lds16(gB + (size_t)(8 * L) * CC + c0, &Bs[(32 * w + 8 * L) * 64]);
    }
    __syncthreads();
    const unsigned short* Af = vmode ? Bs : As;
    const unsigned short* Bf = vmode ? As : Bs;
#pragma unroll
    for (int ks = 0; ks < 2; ++ks) {
      const int ph = ((ks * 4 + quad) ^ (l16 & 7)) * 8;
      bf16x8 af[4], bfr[4];
#pragma unroll
      for (int i = 0; i < 4; ++i) {
        af[i]  = *(const bf16x8*)&Af[(m_off + 16 * i + l16) * 64 + ph];
        bfr[i] = *(const bf16x8*)&Bf[(n_off + 16 * i + l16) * 64 + ph];
      }
#pragma unroll
      for (int i = 0; i < 4; ++i)
#pragma unroll
        for (int j = 0; j < 4; ++j)
          acc[i][j] = __builtin_amdgcn_mfma_f32_16x16x32_bf16(af[i], bfr[j], acc[i][j], 0, 0, 0);
    }
  }

  __syncthreads();
  const float sc = (which == 0) ? QSCALE : 1.0f;
#pragma unroll
  for (int i = 0; i < 4; ++i) {
#pragma unroll
    for (int j = 0; j < 4; ++j) {
      const int Drow = m_off + 16 * i + quad * 4;
      const int Dcol = n_off + 16 * j + l16;
      ushort4 p;
      p.x = f2bf(acc[i][j][0] * sc);
      p.y = f2bf(acc[i][j][1] * sc);
      p.z = f2bf(acc[i][j][2] * sc);
      p.w = f2bf(acc[i][j][3] * sc);
      *(ushort4*)&sm[Dcol * 136 + Drow] = p;
    }
  }
  __syncthreads();
  const int lrow = t >> 1;
  const int half = t & 1;
  const unsigned short* src = &sm[lrow * 136 + 64 * half];
  if (!vmode) {
    const int hh = ((o0 >> 6) & 7) + half;
    unsigned short* dst = (which == 0 ? qb : kb_) +
        ((size_t)(b * NH + hh) * NN + n0 + lrow) * HD;
#pragma unroll
    for (int i = 0; i < 8; ++i) *(uint4*)(dst + 8 * i) = *(const uint4*)(src + 8 * i);
  } else {
    const int hh = ((o0 + lrow) >> 6) & 7;
    const int d  = lrow & 63;
    unsigned short* dst = vt + ((size_t)(b * NH + hh) * HD + d) * NN + n0 + 64 * half;
#pragma unroll
    for (int i = 0; i < 8; ++i) *(uint4*)(dst + 8 * i) = *(const uint4*)(src + 8 * i);
  }
}

// ---------------------------------------------------------------------------
// attn_mfma v13b: split-K over keys (v13) with the SPILL FIX.
// R12 diagnosis: __launch_bounds__(512,4) forced a 128-VGPR cap; compiler
// collapsed to 64 VGPR and spilled the f32x16 accumulators to scratch
// (FETCH 733MB, WRITE 914MB of spill traffic, attn 363us). v13b relaxes to
// __launch_bounds__(512,2) (cap 256): compiler allocates what the v9-body
// needs (~100-120 VGPR). If that lands <=128, the HW still fits 4 waves/
// SIMD naturally (512 VGPR/SIMD pool) -> the intended occupancy doubling
// without forced spills. Split semantics unchanged (exact combine:
// O=O0+O1, l=l0+l1 under max-free exp2 softmax; verified passing in R12).
// ---------------------------------------------------------------------------
__global__ __launch_bounds__(512, 2) void attn_mfma(const unsigned short* __restrict__ Qg,
                                                    const unsigned short* __restrict__ Kg,
                                                    const unsigned short* __restrict__ Vtg,
                                                    unsigned short* __restrict__ attnB) {
  const int bh = blockIdx.x;     // id % 8 == bh % 8 -> XCD affinity
  const int b  = bh >> 3;
  const int h  = bh & 7;
  const int n0 = blockIdx.y * 256;
  const int t  = threadIdx.x;
  const int w    = t >> 6;        // 0..7
  const int s    = w >> 2;        // key-split 0/1
  const int ws   = w & 3;         // wave-in-split 0..3
  const int lane = t & 63;
  const int l31  = lane & 31;
  const int hi   = lane >> 5;

  // K bufs: (2s+p)*4096 shorts (sm[0,16384));  V bufs: 16384 + (2s+p)*4096
  __shared__ unsigned short sm[32768];   // 64 KiB

  // two query groups per wave: A = n0 + ws*64 + l31, B = A + 32
  const unsigned short* qrow = Qg + ((size_t)bh * NN + n0 + ws * 64 + l31) * HD + hi * 8;
  bf16x8 qfA[4], qfB[4];
#pragma unroll
  for (int c = 0; c < 4; ++c) {
    qfA[c] = *(const bf16x8*)(qrow + 16 * c);
    qfB[c] = *(const bf16x8*)(qrow + 32 * HD + 16 * c);
  }

  // K A-row permutation: rho(l) swaps bits 2 and 3
  const int krow = (l31 & ~12) | ((l31 & 4) << 1) | ((l31 & 8) >> 1);
  const int ksw  = (krow >> 2) & 7;
  const int vsw  = (l31 >> 2) & 7;

  const f32x16 fz = {};
  f32x16 oaccA[2] = {}, oaccB[2] = {};   // O^T partial: D[m=d][n=query]
  float lxA = 0.f, lyA = 0.f, lxB = 0.f, lyB = 0.f;

  // staging (v8 pattern per split, chunk=64): wave ws covers rows
  // [16ws,16ws+16) of K (keys rel. to split) and V^T (d). Source col
  // pre-swizzled with the (row>>2) involution.
  const int srow = lane >> 3;                     // 0..7
  const int sgA  = (lane & 7) ^ ((4 * ws + (srow >> 2)) & 7);
  const int sgB  = (lane & 7) ^ ((4 * ws + 2 + (srow >> 2)) & 7);
  const int kbase = s * 512;                      // this split's key offset
  const unsigned short* kstA = Kg + (size_t)bh * NN * HD +
                               (size_t)(kbase + 16 * ws + srow) * HD + sgA * 8;
  const unsigned short* kstB = Kg + (size_t)bh * NN * HD +
                               (size_t)(kbase + 16 * ws + 8 + srow) * HD + sgB * 8;
  const unsigned short* vstA = Vtg + (size_t)bh * HD * NN +
                               (size_t)(16 * ws + srow) * NN + kbase + sgA * 8;
  const unsigned short* vstB = Vtg + (size_t)bh * HD * NN +
                               (size_t)(16 * ws + 8 + srow) * NN + kbase + sgB * 8;
  const int kso0 = (16 * ws) * 64;
  const int kso1 = (16 * ws + 8) * 64;

  // stage one 64-key chunk (rel. offset j0 in [0,512)) into split buffer p
  auto stage = [&](int j0, int p) {
    unsigned short* Kp = sm + (2 * s + p) * 4096;
    unsigned short* Vp = sm + 16384 + (2 * s + p) * 4096;
    gld_lds16(kstA + (size_t)j0 * HD, Kp + kso0);
    gld_lds16(kstB + (size_t)j0 * HD, Kp + kso1);
    gld_lds16(vstA + j0, Vp + kso0);
    gld_lds16(vstB + j0, Vp + kso1);
  };

  // prologue: chunk 0 into buffer 0
  stage(0, 0);
  int cur = 0;

#pragma unroll 1
  for (int j0 = 0; j0 < 512; j0 += 64) {
    // implicit s_waitcnt vmcnt(0) here drains chunk-j0 loads (in flight for
    // a full compute phase), then publishes them to all waves.
    __syncthreads();
    if (j0 + 64 < 512) stage(j0 + 64, cur ^ 1);

    const unsigned short* Ks = sm + (2 * s + cur) * 4096;          // [key][d]
    const unsigned short* Vt = sm + 16384 + (2 * s + cur) * 4096;  // [d][key]

#pragma unroll
    for (int kb = 0; kb < 2; ++kb) {
      // S^T: A[m]=K row rho(m) (32 keys), B=Q; contract over d.
      // kf read ONCE from LDS, feeds both query groups.
      const unsigned short* krp = &Ks[(32 * kb + krow) * 64];
      __builtin_amdgcn_s_setprio(1);
      bf16x8 kf0 = *(const bf16x8*)(krp + (((0 + hi) ^ ksw) * 8));
      f32x16 stA = __builtin_amdgcn_mfma_f32_32x32x16_bf16(kf0, qfA[0], fz, 0, 0, 0);
      f32x16 stB = __builtin_amdgcn_mfma_f32_32x32x16_bf16(kf0, qfB[0], fz, 0, 0, 0);
#pragma unroll
      for (int c = 1; c < 4; ++c) {
        bf16x8 kf = *(const bf16x8*)(krp + (((2 * c + hi) ^ ksw) * 8));
        stA = __builtin_amdgcn_mfma_f32_32x32x16_bf16(kf, qfA[c], stA, 0, 0, 0);
        stB = __builtin_amdgcn_mfma_f32_32x32x16_bf16(kf, qfB[c], stB, 0, 0, 0);
      }
      __builtin_amdgcn_s_setprio(0);
      // exp2 (Q carries log2e/8) + l accum + pack; P pairs ARE the PV
      // B-fragment (key permutation absorbed rho)
      unsigned PA[8], PB[8];
#pragma unroll
      for (int i = 0; i < 8; ++i) {
        float ea = EXP2F(stA[2 * i]);
        float eb = EXP2F(stA[2 * i + 1]);
        lxA += ea; lyA += eb;
        PA[i] = pk2bf(ea, eb);
      }
#pragma unroll
      for (int i = 0; i < 8; ++i) {
        float ea = EXP2F(stB[2 * i]);
        float eb = EXP2F(stB[2 * i + 1]);
        lxB += ea; lyB += eb;
        PB[i] = pk2bf(ea, eb);
      }

      __builtin_amdgcn_s_setprio(1);
#pragma unroll
      for (int g = 0; g < 2; ++g) {
        union { unsigned u[4]; bf16x8 v; } cvA, cvB;
        cvA.u[0] = PA[4 * g + 0]; cvA.u[1] = PA[4 * g + 1];
        cvA.u[2] = PA[4 * g + 2]; cvA.u[3] = PA[4 * g + 3];
        cvB.u[0] = PB[4 * g + 0]; cvB.u[1] = PB[4 * g + 1];
        cvB.u[2] = PB[4 * g + 2]; cvB.u[3] = PB[4 * g + 3];
#pragma unroll
        for (int mt = 0; mt < 2; ++mt) {
          const int vrow = 32 * mt + l31;
          // vf read ONCE from LDS, feeds both query groups.
          bf16x8 vf = *(const bf16x8*)&Vt[vrow * 64 + (((4 * kb + 2 * g + hi) ^ vsw) * 8)];
          oaccA[mt] = __builtin_amdgcn_mfma_f32_32x32x16_bf16(vf, cvA.v, oaccA[mt], 0, 0, 0);
          oaccB[mt] = __builtin_amdgcn_mfma_f32_32x32x16_bf16(vf, cvB.v, oaccB[mt], 0, 0, 0);
        }
      }
      __builtin_amdgcn_s_setprio(0);
    }
    cur ^= 1;
  }

  // ---- split combine: O = O0+O1, l = l0+l1 (exact: max-free softmax) ----
  float plA = lxA + lyA;           // per-lane partial l (pre-shuffle)
  float plB = lxB + lyB;
  float* CB = (float*)sm;
  // per wave-pair region: CB[ws*2176 .. +2176), layout lane*34 + idx
  // (stride 136B -> float2 writes land 2-way on banks = free).
  // l partials at CB[8704 + ws*128 + lane*2 + {0,1}].

  __syncthreads();                 // all compute + staging LDS reads done
  if (s == 1) {
    float* R = CB + ws * 2176;
#pragma unroll
    for (int mt = 0; mt < 2; ++mt)
#pragma unroll
      for (int r = 0; r < 8; ++r)
        *(float2*)&R[lane * 34 + mt * 16 + 2 * r] =
            make_float2(oaccA[mt][2 * r], oaccA[mt][2 * r + 1]);
    CB[8704 + ws * 128 + lane * 2 + 0] = plA;
    CB[8704 + ws * 128 + lane * 2 + 1] = plB;
  }
  __syncthreads();
  if (s == 0) {
    float* R = CB + ws * 2176;
#pragma unroll
    for (int mt = 0; mt < 2; ++mt)
#pragma unroll
      for (int r = 0; r < 8; ++r) {
        float2 v = *(const float2*)&R[lane * 34 + mt * 16 + 2 * r];
        oaccA[mt][2 * r]     += v.x;
        oaccA[mt][2 * r + 1] += v.y;
      }
    plA += CB[8704 + ws * 128 + lane * 2 + 0];
    plB += CB[8704 + ws * 128 + lane * 2 + 1];
  }
  __syncthreads();
  if (s == 1) {
    float* R = CB + ws * 2176;
#pragma unroll
    for (int mt = 0; mt < 2; ++mt)
#pragma unroll
      for (int r = 0; r < 8; ++r)
        *(float2*)&R[lane * 34 + mt * 16 + 2 * r] =
            make_float2(oaccB[mt][2 * r], oaccB[mt][2 * r + 1]);
  }
  __syncthreads();
  if (s == 0) {
    float* R = CB + ws * 2176;
#pragma unroll
    for (int mt = 0; mt < 2; ++mt)
#pragma unroll
      for (int r = 0; r < 8; ++r) {
        float2 v = *(const float2*)&R[lane * 34 + mt * 16 + 2 * r];
        oaccB[mt][2 * r]     += v.x;
        oaccB[mt][2 * r + 1] += v.y;
      }
  }
  __syncthreads();                 // all combine reads done; CB reusable

  // ---- final epilogue: split-0 waves only (they own the summed state) ----
  if (s == 0) {
    float lsA = plA;
    lsA += __shfl_xor(lsA, 32);
    const float invA = 1.0f / lsA;
    float lsB = plB;
    lsB += __shfl_xor(lsB, 32);
    const float invB = 1.0f / lsB;

    unsigned short* Es = sm + ws * 2304;   // 32 * 72 shorts per wave
    const int q    = lane >> 1;
    const int half = lane & 1;
    const unsigned short* esrc = &Es[q * 72 + 32 * half];

    // ---- pass A ----
#pragma unroll
    for (int mt = 0; mt < 2; ++mt) {
#pragma unroll
      for (int rr = 0; rr < 4; ++rr) {
        const int d = 32 * mt + 8 * rr + 4 * hi;
        ushort4 p;
        p.x = f2bf(oaccA[mt][4 * rr + 0] * invA);
        p.y = f2bf(oaccA[mt][4 * rr + 1] * invA);
        p.z = f2bf(oaccA[mt][4 * rr + 2] * invA);
        p.w = f2bf(oaccA[mt][4 * rr + 3] * invA);
        *(ushort4*)&Es[l31 * 72 + d] = p;
      }
    }
    {
      unsigned short* gdst = attnB + ((size_t)b * NN + n0 + ws * 64 + q) * CC + h * HD + 32 * half;
#pragma unroll
      for (int i = 0; i < 4; ++i) *(uint4*)(gdst + 8 * i) = *(const uint4*)(esrc + 8 * i);
    }

    // ---- pass B (same wave-private region; in-wave deps order LDS ops) ----
#pragma unroll
    for (int mt = 0; mt < 2; ++mt) {
#pragma unroll
      for (int rr = 0; rr < 4; ++rr) {
        const int d = 32 * mt + 8 * rr + 4 * hi;
        ushort4 p;
        p.x = f2bf(oaccB[mt][4 * rr + 0] * invB);
        p.y = f2bf(oaccB[mt][4 * rr + 1] * invB);
        p.z = f2bf(oaccB[mt][4 * rr + 2] * invB);
        p.w = f2bf(oaccB[mt][4 * rr + 3] * invB);
        *(ushort4*)&Es[l31 * 72 + d] = p;
      }
    }
    {
      unsigned short* gdst = attnB + ((size_t)b * NN + n0 + ws * 64 + 32 + q) * CC + h * HD + 32 * half;
#pragma unroll
      for (int i = 0; i < 4; ++i) *(uint4*)(gdst + 8 * i) = *(const uint4*)(esrc + 8 * i);
    }
  }
}

// ---------------------------------------------------------------------------
// proj_mfma: out = w_proj @ attn + bias, bf16 MFMA, fp32 out [b][c][n].
// ---------------------------------------------------------------------------
__global__ __launch_bounds__(256) void proj_mfma(const unsigned short* __restrict__ wp,
                                                 const unsigned short* __restrict__ aB,
                                                 const float* __restrict__ bias,
                                                 float* __restrict__ out) {
  const int b  = blockIdx.z;
  const int o0 = blockIdx.y * 128;
  const int n0 = blockIdx.x * 128;
  const int t  = threadIdx.x;
  const int w    = t >> 6;
  const int lane = t & 63;
  const int quad = lane >> 4;
  const int l16  = lane & 15;
  const int m_off = (w >> 1) * 64;
  const int n_off = (w & 1) * 64;

  __shared__ unsigned short sm[16384];
  unsigned short* As = sm;
  unsigned short* Bs = sm + 8192;

  const int srow = lane >> 3;
  const int ssw  = ((lane & 7) ^ srow) * 8;
  const unsigned short* gA = wp + (size_t)(o0 + 32 * w + srow) * CC + ssw;
  const unsigned short* gB = aB + ((size_t)b * NN + n0 + 32 * w + srow) * CC + ssw;

  f32x4 acc[4][4] = {};

  for (int c0 = 0; c0 < CC; c0 += 64) {
    __syncthreads();
#pragma unroll
    for (int L = 0; L < 4; ++L) {
      gld_lds16(gA + (size_t)(8 * L) * CC + c0, &As[(32 * w + 8 * L) * 64]);
      gld_lds16(gB + (size_t)(8 * L) * CC + c0, &Bs[(32 * w + 8 * L) * 64]);
    }
    __syncthreads();
#pragma unroll
    for (int ks = 0; ks < 2; ++ks) {
      const int ph = ((ks * 4 + quad) ^ (l16 & 7)) * 8;
      bf16x8 af[4], bfr[4];
#pragma unroll
      for (int i = 0; i < 4; ++i) {
        af[i]  = *(const bf16x8*)&As[(m_off + 16 * i + l16) * 64 + ph];
        bfr[i] = *(const bf16x8*)&Bs[(n_off + 16 * i + l16) * 64 + ph];
      }
#pragma unroll
      for (int i = 0; i < 4; ++i)
#pragma unroll
        for (int j = 0; j < 4; ++j)
          acc[i][j] = __builtin_amdgcn_mfma_f32_16x16x32_bf16(af[i], bfr[j], acc[i][j], 0, 0, 0);
    }
  }

#pragma unroll
  for (int i = 0; i < 4; ++i) {
#pragma unroll
    for (int r = 0; r < 4; ++r) {
      const int o = o0 + m_off + 16 * i + quad * 4 + r;
      const float bv = bias[o];
      float* orow = out + ((size_t)b * CC + o) * NN + n0 + n_off;
#pragma unroll
      for (int j = 0; j < 4; ++j)
        orow[16 * j + l16] = acc[i][j][r] + bv;
    }
  }
}

// ---------------------------------------------------------------------------
extern "C" void kernel_launch(void* const* d_in, const int* in_sizes, int n_in,
                              void* d_out, int out_size, void* d_ws, size_t ws_size,
                              hipStream_t stream) {
  const float* x      = (const float*)d_in[0];
  const float* w_qkv  = (const float*)d_in[1];
  const float* w_proj = (const float*)d_in[2];
  const float* b_proj = (const float*)d_in[3];
  char* wsb  = (char*)d_ws;
  float* out = (float*)d_out;

  unsigned short* xT  = (unsigned short*)(wsb + XT_OFF);
  unsigned short* wq  = (unsigned short*)(wsb + WQ_OFF);
  unsigned short* wp  = (unsigned short*)(wsb + WP_OFF);
  unsigned short* qb  = (unsigned short*)(wsb + QB_OFF);
  unsigned short* kb_ = (unsigned short*)(wsb + KB_OFF);
  unsigned short* vt  = (unsigned short*)(wsb + VT_OFF);
  unsigned short* aB  = (unsigned short*)(wsb + AB_OFF);

  prep_fused<<<dim3(16, 8, BB), 256, 0, stream>>>(x, xT, w_qkv, w_proj, wq, wp);
  qkv_mfma<<<dim3(8, 12, BB), 256, 0, stream>>>(wq, xT, qb, kb_, vt);
  attn_mfma<<<dim3(BB * NH, NN / 256), 512, 0, stream>>>(qb, kb_, vt, aB);
  proj_mfma<<<dim3(8, 4, BB), 256, 0, stream>>>(wp, aB, b_proj, out);
}

// Round 14
// 188.733 us; speedup vs baseline: 2.6306x; 1.0276x over previous
//
#include <hip/hip_runtime.h>
#include <hip/hip_bf16.h>
#include <math.h>

#define BB 16
#define CC 512
#define NH 8
#define HD 64
#define NN 1024   // H*W
#define THREEC 1536

// Q pre-scale: (1/sqrt(64)) * log2(e)  -> softmax via raw v_exp_f32 (2^x)
#define QSCALE 0.18033688f

typedef __attribute__((ext_vector_type(8))) short bf16x8;
typedef __attribute__((ext_vector_type(4))) float f32x4;
typedef __attribute__((ext_vector_type(16))) float f32x16;

#if __has_builtin(__builtin_amdgcn_exp2f)
#define EXP2F __builtin_amdgcn_exp2f
#else
#define EXP2F exp2f
#endif

// workspace byte offsets
#define XT_OFF 0u           // bf16 x^T [b][n][c]          (16.78 MB)
#define WQ_OFF 16777216u    // bf16 w_qkv [1536][512]      (1.57 MB)
#define WP_OFF 18350080u    // bf16 w_proj [512][512]      (0.52 MB)
#define QB_OFF 18874368u    // bf16 Q (scaled QSCALE) [bh][n][d]
#define KB_OFF 35651584u    // bf16 K [bh][n][d]
#define VT_OFF 52428800u    // bf16 V^T [bh][d][n]
#define AB_OFF 69206016u    // bf16 attn-out [b][n][c]
// end 85983232 (82 MiB)

static __device__ inline unsigned short f2bf(float f) {
  union { float f; unsigned u; } v; v.f = f;
  unsigned r = v.u + 0x7fffu + ((v.u >> 16) & 1u);
  return (unsigned short)(r >> 16);
}

// pack two f32 -> two bf16 in a u32 (lo = a, hi = b)
static __device__ inline unsigned pk2bf(float a, float b) {
#if defined(__AMDGCN__) && __has_builtin(__builtin_amdgcn_cvt_pk_bf16_f32)
  typedef __attribute__((ext_vector_type(2))) __bf16 bfp2;
  union { bfp2 v; unsigned u; } z;
  z.v = __builtin_amdgcn_cvt_pk_bf16_f32(a, b);
  return z.u;
#else
  return (unsigned)f2bf(a) | ((unsigned)f2bf(b) << 16);
#endif
}

static __device__ inline void gld_lds16(const unsigned short* g, unsigned short* l) {
  __builtin_amdgcn_global_load_lds(
      (const __attribute__((address_space(1))) unsigned int*)g,
      (__attribute__((address_space(3))) unsigned int*)l, 16, 0, 0);
}

// ---------------------------------------------------------------------------
// prep_fused: x [b][c][n] fp32 -> xT [b][n][c] bf16 (64x64 LDS transpose),
// PLUS (first 512 blocks) w_qkv/w_proj fp32 -> bf16 conversion folded in.
// ---------------------------------------------------------------------------
__global__ __launch_bounds__(256) void prep_fused(const float* __restrict__ x,
                                                  unsigned short* __restrict__ xT,
                                                  const float* __restrict__ wqkv,
                                                  const float* __restrict__ wproj,
                                                  unsigned short* __restrict__ dq,
                                                  unsigned short* __restrict__ dp) {
  const int b  = blockIdx.z;
  const int c0 = blockIdx.y * 64;
  const int n0 = blockIdx.x * 64;
  __shared__ float tile[64][65];
  const int t  = threadIdx.x;

  // ---- folded prep_w: blocks with wid < 512 ----
  const int wid = (blockIdx.z * 8 + blockIdx.y) * 16 + blockIdx.x;
  if (wid < 512) {
    const size_t i8 = ((size_t)wid * 256 + t) * 8;
    const float* src;
    unsigned short* dst;
    if (i8 < 786432u) { src = wqkv + i8; dst = dq + i8; }
    else              { src = wproj + (i8 - 786432u); dst = dp + (i8 - 786432u); }
    float4 a = *(const float4*)src;
    float4 b4 = *(const float4*)(src + 4);
    unsigned short pk[8] = {f2bf(a.x), f2bf(a.y), f2bf(a.z), f2bf(a.w),
                            f2bf(b4.x), f2bf(b4.y), f2bf(b4.z), f2bf(b4.w)};
    *(uint4*)dst = *(const uint4*)pk;
  }

  // ---- xT transpose ----
  const int cl = t >> 4, n4 = (t & 15) * 4;
#pragma unroll
  for (int r = 0; r < 4; ++r) {
    float4 v = *(const float4*)&x[((size_t)b * CC + c0 + cl + 16 * r) * NN + n0 + n4];
    *(float4*)&tile[cl + 16 * r][n4] = v;
  }
  __syncthreads();
  const int nl = t >> 4, c4 = (t & 15) * 4;
#pragma unroll
  for (int r = 0; r < 4; ++r) {
    ushort4 p;
    p.x = f2bf(tile[c4 + 0][nl + 16 * r]);
    p.y = f2bf(tile[c4 + 1][nl + 16 * r]);
    p.z = f2bf(tile[c4 + 2][nl + 16 * r]);
    p.w = f2bf(tile[c4 + 3][nl + 16 * r]);
    *(ushort4*)&xT[((size_t)b * NN + n0 + nl + 16 * r) * CC + c0 + c4] = p;
  }
}

// ---------------------------------------------------------------------------
// qkv_mfma: [1536x512] @ [512x1024] per batch, bf16 MFMA, 128x128 tile BK=64.
// ---------------------------------------------------------------------------
__global__ __launch_bounds__(256) void qkv_mfma(const unsigned short* __restrict__ wq,
                                                const unsigned short* __restrict__ xT,
                                                unsigned short* __restrict__ qb,
                                                unsigned short* __restrict__ kb_,
                                                unsigned short* __restrict__ vt) {
  const int b  = blockIdx.z;
  const int o0 = blockIdx.y * 128;
  const int n0 = blockIdx.x * 128;
  const int t  = threadIdx.x;
  const int w    = t >> 6;
  const int lane = t & 63;
  const int quad = lane >> 4;
  const int l16  = lane & 15;
  const int m_off = (w >> 1) * 64;
  const int n_off = (w & 1) * 64;

  __shared__ unsigned short sm[17408];
  unsigned short* As = sm;
  unsigned short* Bs = sm + 8192;

  const int which = o0 >> 9;       // 0=Q,1=K,2=V
  const bool vmode = (which == 2);

  const int srow = lane >> 3;
  const int ssw  = ((lane & 7) ^ srow) * 8;
  const unsigned short* gA = wq + (size_t)(o0 + 32 * w + srow) * CC + ssw;
  const unsigned short* gB = xT + ((size_t)b * NN + n0 + 32 * w + srow) * CC + ssw;

  f32x4 acc[4][4] = {};

  for (int c0 = 0; c0 < CC; c0 += 64) {
    __syncthreads();
#pragma unroll
    for (int L = 0; L < 4; ++L) {
      gld_lds16(gA + (size_t)(8 * L) * CC + c0, &As[(32 * w + 8 * L) * 64]);
      gld_lds16(gB + (size_t)(8 * L) * CC + c0, &Bs[(32 * w + 8 * L) * 64]);
    }
    __syncthreads();
    const unsigned short* Af = vmode ? Bs : As;
    const unsigned short* Bf = vmode ? As : Bs;
#pragma unroll
    for (int ks = 0; ks < 2; ++ks) {
      const int ph = ((ks * 4 + quad) ^ (l16 & 7)) * 8;
      bf16x8 af[4], bfr[4];
#pragma unroll
      for (int i = 0; i < 4; ++i) {
        af[i]  = *(const bf16x8*)&Af[(m_off + 16 * i + l16) * 64 + ph];
        bfr[i] = *(const bf16x8*)&Bf[(n_off + 16 * i + l16) * 64 + ph];
      }
#pragma unroll
      for (int i = 0; i < 4; ++i)
#pragma unroll
        for (int j = 0; j < 4; ++j)
          acc[i][j] = __builtin_amdgcn_mfma_f32_16x16x32_bf16(af[i], bfr[j], acc[i][j], 0, 0, 0);
    }
  }

  __syncthreads();
  const float sc = (which == 0) ? QSCALE : 1.0f;
#pragma unroll
  for (int i = 0; i < 4; ++i) {
#pragma unroll
    for (int j = 0; j < 4; ++j) {
      const int Drow = m_off + 16 * i + quad * 4;
      const int Dcol = n_off + 16 * j + l16;
      ushort4 p;
      p.x = f2bf(acc[i][j][0] * sc);
      p.y = f2bf(acc[i][j][1] * sc);
      p.z = f2bf(acc[i][j][2] * sc);
      p.w = f2bf(acc[i][j][3] * sc);
      *(ushort4*)&sm[Dcol * 136 + Drow] = p;
    }
  }
  __syncthreads();
  const int lrow = t >> 1;
  const int half = t & 1;
  const unsigned short* src = &sm[lrow * 136 + 64 * half];
  if (!vmode) {
    const int hh = ((o0 >> 6) & 7) + half;
    unsigned short* dst = (which == 0 ? qb : kb_) +
        ((size_t)(b * NH + hh) * NN + n0 + lrow) * HD;
#pragma unroll
    for (int i = 0; i < 8; ++i) *(uint4*)(dst + 8 * i) = *(const uint4*)(src + 8 * i);
  } else {
    const int hh = ((o0 + lrow) >> 6) & 7;
    const int d  = lrow & 63;
    unsigned short* dst = vt + ((size_t)(b * NH + hh) * HD + d) * NN + n0 + 64 * half;
#pragma unroll
    for (int i = 0; i < 8; ++i) *(uint4*)(dst + 8 * i) = *(const uint4*)(src + 8 * i);
  }
}

// ---------------------------------------------------------------------------
// attn_mfma v9 FINAL (proven best; R8 total 184.6us, attn 47.7-48.5us):
// 64 q/wave (qfA/qfB share every K/V LDS read), chunk=128 double-buffered
// stage-after-barrier, (row>>2) involution swizzle, 256 thr / 2 blocks/CU.
// Closed levers (all measured to falsification): lacc-on-MFMA (v5),
// skewed pipe (v6), direct-from-L2 (v7), fused-kb ILP (v10/v12: hipcc
// re-serializes), 1-block/CU (v11), split-K occupancy (v13/v13b: spill,
// then LDS-pipe saturation at 4 waves/SIMD + duplicate Q fetch).
// SQ_LDS_BANK_CONFLICT 2.29M = intrinsic ~4.4cyc/ds_read_b128.
// This structure sits at the LDS-pipe/trans-pipe/MFMA/latency equilibrium.
// ---------------------------------------------------------------------------
__global__ __launch_bounds__(256, 2) void attn_mfma(const unsigned short* __restrict__ Qg,
                                                    const unsigned short* __restrict__ Kg,
                                                    const unsigned short* __restrict__ Vtg,
                                                    unsigned short* __restrict__ attnB) {
  const int bh = blockIdx.x;     // id % 8 == bh % 8 -> XCD affinity
  const int b  = bh >> 3;
  const int h  = bh & 7;
  const int n0 = blockIdx.y * 256;
  const int t  = threadIdx.x;
  const int w    = t >> 6;
  const int lane = t & 63;
  const int l31  = lane & 31;
  const int hi   = lane >> 5;

  // K bufs: p*8192 + half*4096  (sm[0,16384))
  // V bufs: 16384 + p*8192 + half*4096  (sm[16384,32768))
  __shared__ unsigned short sm[32768];   // 64 KiB

  // two query groups per wave: A = n0 + w*64 + l31, B = A + 32
  const unsigned short* qrow = Qg + ((size_t)bh * NN + n0 + w * 64 + l31) * HD + hi * 8;
  bf16x8 qfA[4], qfB[4];
#pragma unroll
  for (int c = 0; c < 4; ++c) {
    qfA[c] = *(const bf16x8*)(qrow + 16 * c);
    qfB[c] = *(const bf16x8*)(qrow + 32 * HD + 16 * c);
  }

  // K A-row permutation: rho(l) swaps bits 2 and 3
  const int krow = (l31 & ~12) | ((l31 & 4) << 1) | ((l31 & 8) >> 1);
  const int ksw  = (krow >> 2) & 7;
  const int vsw  = (l31 >> 2) & 7;

  const f32x16 fz = {};
  f32x16 oaccA[2] = {}, oaccB[2] = {};   // O^T: D[m=d][n=query]
  float lxA = 0.f, lyA = 0.f, lxB = 0.f, lyB = 0.f;

  // staging: wave w covers rows [16w,16w+16) of both K (keys) and V^T (d),
  // per 64-row half. Source col pre-swizzled with the (row>>2) involution.
  const int srow = lane >> 3;                     // 0..7
  const int sgA  = (lane & 7) ^ ((4 * w + (srow >> 2)) & 7);
  const int sgB  = (lane & 7) ^ ((4 * w + 2 + (srow >> 2)) & 7);
  const unsigned short* kstA = Kg + (size_t)bh * NN * HD +
                               (size_t)(16 * w + srow) * HD + sgA * 8;
  const unsigned short* kstB = Kg + (size_t)bh * NN * HD +
                               (size_t)(16 * w + 8 + srow) * HD + sgB * 8;
  const unsigned short* vstA = Vtg + (size_t)bh * HD * NN +
                               (size_t)(16 * w + srow) * NN + sgA * 8;
  const unsigned short* vstB = Vtg + (size_t)bh * HD * NN +
                               (size_t)(16 * w + 8 + srow) * NN + sgB * 8;
  const int kso0 = (16 * w) * 64;
  const int kso1 = (16 * w + 8) * 64;

  // stage one 128-key chunk (two 64-key halves) into buffer p
  auto stage = [&](int j0, int p) {
#pragma unroll
    for (int hf = 0; hf < 2; ++hf) {
      unsigned short* Kp = sm + p * 8192 + hf * 4096;
      unsigned short* Vp = sm + 16384 + p * 8192 + hf * 4096;
      const int jo = j0 + 64 * hf;
      gld_lds16(kstA + (size_t)jo * HD, Kp + kso0);
      gld_lds16(kstB + (size_t)jo * HD, Kp + kso1);
      gld_lds16(vstA + jo, Vp + kso0);
      gld_lds16(vstB + jo, Vp + kso1);
    }
  };

  // prologue: chunk 0 into buffer 0
  stage(0, 0);
  int cur = 0;

#pragma unroll 1
  for (int j0 = 0; j0 < NN; j0 += 128) {
    // implicit s_waitcnt vmcnt(0) here drains chunk-j0 loads (in flight for
    // a full 128-key compute phase), then publishes them to all waves.
    __syncthreads();
    if (j0 + 128 < NN) stage(j0 + 128, cur ^ 1);

#pragma unroll
    for (int hf = 0; hf < 2; ++hf) {
      const unsigned short* Ks = sm + cur * 8192 + hf * 4096;          // [key][d]
      const unsigned short* Vt = sm + 16384 + cur * 8192 + hf * 4096;  // [d][key]

#pragma unroll
      for (int kb = 0; kb < 2; ++kb) {
        // S^T: A[m]=K row rho(m) (32 keys), B=Q; contract over d.
        // kf read ONCE from LDS, feeds both query groups.
        const unsigned short* krp = &Ks[(32 * kb + krow) * 64];
        __builtin_amdgcn_s_setprio(1);
        bf16x8 kf0 = *(const bf16x8*)(krp + (((0 + hi) ^ ksw) * 8));
        f32x16 stA = __builtin_amdgcn_mfma_f32_32x32x16_bf16(kf0, qfA[0], fz, 0, 0, 0);
        f32x16 stB = __builtin_amdgcn_mfma_f32_32x32x16_bf16(kf0, qfB[0], fz, 0, 0, 0);
#pragma unroll
        for (int c = 1; c < 4; ++c) {
          bf16x8 kf = *(const bf16x8*)(krp + (((2 * c + hi) ^ ksw) * 8));
          stA = __builtin_amdgcn_mfma_f32_32x32x16_bf16(kf, qfA[c], stA, 0, 0, 0);
          stB = __builtin_amdgcn_mfma_f32_32x32x16_bf16(kf, qfB[c], stB, 0, 0, 0);
        }
        __builtin_amdgcn_s_setprio(0);
        // exp2 (Q carries log2e/8) + l accum + pack; P pairs ARE the PV
        // B-fragment (key permutation absorbed rho)
        unsigned PA[8], PB[8];
#pragma unroll
        for (int i = 0; i < 8; ++i) {
          float ea = EXP2F(stA[2 * i]);
          float eb = EXP2F(stA[2 * i + 1]);
          lxA += ea; lyA += eb;
          PA[i] = pk2bf(ea, eb);
        }
#pragma unroll
        for (int i = 0; i < 8; ++i) {
          float ea = EXP2F(stB[2 * i]);
          float eb = EXP2F(stB[2 * i + 1]);
          lxB += ea; lyB += eb;
          PB[i] = pk2bf(ea, eb);
        }

        __builtin_amdgcn_s_setprio(1);
#pragma unroll
        for (int g = 0; g < 2; ++g) {
          union { unsigned u[4]; bf16x8 v; } cvA, cvB;
          cvA.u[0] = PA[4 * g + 0]; cvA.u[1] = PA[4 * g + 1];
          cvA.u[2] = PA[4 * g + 2]; cvA.u[3] = PA[4 * g + 3];
          cvB.u[0] = PB[4 * g + 0]; cvB.u[1] = PB[4 * g + 1];
          cvB.u[2] = PB[4 * g + 2]; cvB.u[3] = PB[4 * g + 3];
#pragma unroll
          for (int mt = 0; mt < 2; ++mt) {
            const int vrow = 32 * mt + l31;
            // vf read ONCE from LDS, feeds both query groups.
            bf16x8 vf = *(const bf16x8*)&Vt[vrow * 64 + (((4 * kb + 2 * g + hi) ^ vsw) * 8)];
            oaccA[mt] = __builtin_amdgcn_mfma_f32_32x32x16_bf16(vf, cvA.v, oaccA[mt], 0, 0, 0);
            oaccB[mt] = __builtin_amdgcn_mfma_f32_32x32x16_bf16(vf, cvB.v, oaccB[mt], 0, 0, 0);
          }
        }
        __builtin_amdgcn_s_setprio(0);
      }
    }
    cur ^= 1;
  }

  float lsA = lxA + lyA;
  lsA += __shfl_xor(lsA, 32);
  const float invA = 1.0f / lsA;
  float lsB = lxB + lyB;
  lsB += __shfl_xor(lsB, 32);
  const float invB = 1.0f / lsB;

  // epilogue: two wave-private passes through LDS [query][d] (pitch 72),
  // then 64B global writes. Barrier first: staging buffers overlap Es.
  __syncthreads();
  unsigned short* Es = sm + w * 2304;   // 32 * 72 shorts per wave
  const int q    = lane >> 1;
  const int half = lane & 1;
  const unsigned short* esrc = &Es[q * 72 + 32 * half];

  // ---- pass A ----
#pragma unroll
  for (int mt = 0; mt < 2; ++mt) {
#pragma unroll
    for (int rr = 0; rr < 4; ++rr) {
      const int d = 32 * mt + 8 * rr + 4 * hi;
      ushort4 p;
      p.x = f2bf(oaccA[mt][4 * rr + 0] * invA);
      p.y = f2bf(oaccA[mt][4 * rr + 1] * invA);
      p.z = f2bf(oaccA[mt][4 * rr + 2] * invA);
      p.w = f2bf(oaccA[mt][4 * rr + 3] * invA);
      *(ushort4*)&Es[l31 * 72 + d] = p;
    }
  }
  {
    unsigned short* gdst = attnB + ((size_t)b * NN + n0 + w * 64 + q) * CC + h * HD + 32 * half;
#pragma unroll
    for (int i = 0; i < 4; ++i) *(uint4*)(gdst + 8 * i) = *(const uint4*)(esrc + 8 * i);
  }

  // ---- pass B (same wave-private region; in-wave deps order LDS ops) ----
#pragma unroll
  for (int mt = 0; mt < 2; ++mt) {
#pragma unroll
    for (int rr = 0; rr < 4; ++rr) {
      const int d = 32 * mt + 8 * rr + 4 * hi;
      ushort4 p;
      p.x = f2bf(oaccB[mt][4 * rr + 0] * invB);
      p.y = f2bf(oaccB[mt][4 * rr + 1] * invB);
      p.z = f2bf(oaccB[mt][4 * rr + 2] * invB);
      p.w = f2bf(oaccB[mt][4 * rr + 3] * invB);
      *(ushort4*)&Es[l31 * 72 + d] = p;
    }
  }
  {
    unsigned short* gdst = attnB + ((size_t)b * NN + n0 + w * 64 + 32 + q) * CC + h * HD + 32 * half;
#pragma unroll
    for (int i = 0; i < 4; ++i) *(uint4*)(gdst + 8 * i) = *(const uint4*)(esrc + 8 * i);
  }
}

// ---------------------------------------------------------------------------
// proj_mfma: out = w_proj @ attn + bias, bf16 MFMA, fp32 out [b][c][n].
// ---------------------------------------------------------------------------
__global__ __launch_bounds__(256) void proj_mfma(const unsigned short* __restrict__ wp,
                                                 const unsigned short* __restrict__ aB,
                                                 const float* __restrict__ bias,
                                                 float* __restrict__ out) {
  const int b  = blockIdx.z;
  const int o0 = blockIdx.y * 128;
  const int n0 = blockIdx.x * 128;
  const int t  = threadIdx.x;
  const int w    = t >> 6;
  const int lane = t & 63;
  const int quad = lane >> 4;
  const int l16  = lane & 15;
  const int m_off = (w >> 1) * 64;
  const int n_off = (w & 1) * 64;

  __shared__ unsigned short sm[16384];
  unsigned short* As = sm;
  unsigned short* Bs = sm + 8192;

  const int srow = lane >> 3;
  const int ssw  = ((lane & 7) ^ srow) * 8;
  const unsigned short* gA = wp + (size_t)(o0 + 32 * w + srow) * CC + ssw;
  const unsigned short* gB = aB + ((size_t)b * NN + n0 + 32 * w + srow) * CC + ssw;

  f32x4 acc[4][4] = {};

  for (int c0 = 0; c0 < CC; c0 += 64) {
    __syncthreads();
#pragma unroll
    for (int L = 0; L < 4; ++L) {
      gld_lds16(gA + (size_t)(8 * L) * CC + c0, &As[(32 * w + 8 * L) * 64]);
      gld_lds16(gB + (size_t)(8 * L) * CC + c0, &Bs[(32 * w + 8 * L) * 64]);
    }
    __syncthreads();
#pragma unroll
    for (int ks = 0; ks < 2; ++ks) {
      const int ph = ((ks * 4 + quad) ^ (l16 & 7)) * 8;
      bf16x8 af[4], bfr[4];
#pragma unroll
      for (int i = 0; i < 4; ++i) {
        af[i]  = *(const bf16x8*)&As[(m_off + 16 * i + l16) * 64 + ph];
        bfr[i] = *(const bf16x8*)&Bs[(n_off + 16 * i + l16) * 64 + ph];
      }
#pragma unroll
      for (int i = 0; i < 4; ++i)
#pragma unroll
        for (int j = 0; j < 4; ++j)
          acc[i][j] = __builtin_amdgcn_mfma_f32_16x16x32_bf16(af[i], bfr[j], acc[i][j], 0, 0, 0);
    }
  }

#pragma unroll
  for (int i = 0; i < 4; ++i) {
#pragma unroll
    for (int r = 0; r < 4; ++r) {
      const int o = o0 + m_off + 16 * i + quad * 4 + r;
      const float bv = bias[o];
      float* orow = out + ((size_t)b * CC + o) * NN + n0 + n_off;
#pragma unroll
      for (int j = 0; j < 4; ++j)
        orow[16 * j + l16] = acc[i][j][r] + bv;
    }
  }
}

// ---------------------------------------------------------------------------
extern "C" void kernel_launch(void* const* d_in, const int* in_sizes, int n_in,
                              void* d_out, int out_size, void* d_ws, size_t ws_size,
                              hipStream_t stream) {
  const float* x      = (const float*)d_in[0];
  const float* w_qkv  = (const float*)d_in[1];
  const float* w_proj = (const float*)d_in[2];
  const float* b_proj = (const float*)d_in[3];
  char* wsb  = (char*)d_ws;
  float* out = (float*)d_out;

  unsigned short* xT  = (unsigned short*)(wsb + XT_OFF);
  unsigned short* wq  = (unsigned short*)(wsb + WQ_OFF);
  unsigned short* wp  = (unsigned short*)(wsb + WP_OFF);
  unsigned short* qb  = (unsigned short*)(wsb + QB_OFF);
  unsigned short* kb_ = (unsigned short*)(wsb + KB_OFF);
  unsigned short* vt  = (unsigned short*)(wsb + VT_OFF);
  unsigned short* aB  = (unsigned short*)(wsb + AB_OFF);

  prep_fused<<<dim3(16, 8, BB), 256, 0, stream>>>(x, xT, w_qkv, w_proj, wq, wp);
  qkv_mfma<<<dim3(8, 12, BB), 256, 0, stream>>>(wq, xT, qb, kb_, vt);
  attn_mfma<<<dim3(BB * NH, NN / 256), 256, 0, stream>>>(qb, kb_, vt, aB);
  proj_mfma<<<dim3(8, 4, BB), 256, 0, stream>>>(wp, aB, b_proj, out);
}